// Round 3
// baseline (210.488 us; speedup 1.0000x reference)
//
#include <hip/hip_runtime.h>
#include <hip/hip_bf16.h>

#define FDIM 128
#define BROWS 32     // i1 rows per bucket: bin = i1>>5, loc = i1&31 (5-bit pack)
#define NBLK 256     // partition blocks for hist/scatter

typedef __attribute__((ext_vector_type(8))) short short8v;
typedef __attribute__((ext_vector_type(4))) float f32x4;

// ---- bf16 helpers (manual, RNE) ----
static __device__ __forceinline__ unsigned short f2bf(float x) {
    unsigned u = __float_as_uint(x);
    unsigned r = 0x7fffu + ((u >> 16) & 1u);
    return (unsigned short)((u + r) >> 16);
}
static __device__ __forceinline__ float bf2f(unsigned short h) {
    return __uint_as_float((unsigned)h << 16);
}

// split fp32 -> bf16 hi + bf16 lo (hi+lo reproduces fp32 to ~2^-17 rel)
static __device__ __forceinline__ void split2(float v, short& h, short& l) {
    unsigned short hh = f2bf(v);
    h = (short)hh;
    l = (short)f2bf(v - bf2f(hh));
}

// ---- k1: G = F @ (W + W^T) via MFMA bf16 with 3-term split (fp32-grade accuracy).
// Ws is symmetric => B-operand read as Ws[col][k] from LDS rows (transpose-free).
// Block: 512 thr = 8 waves, each wave a 16-row x 128-col stripe. ----
// (unchanged from round 2 — harness-verified; its correctness also HW-verifies the
//  16x16x32 A/B/D fragment layout reused by edge_kernel below)
__global__ __launch_bounds__(512, 4) void gemm_mfma(
    const float* __restrict__ Fm, const float* __restrict__ W,
    unsigned short* __restrict__ Gbf, int N) {
    __shared__ unsigned short sH[128 * 136];   // +8 bf16 pad
    __shared__ unsigned short sL[128 * 136];

    for (int idx = threadIdx.x; idx < 128 * 128; idx += 512) {
        int i = idx >> 7, j = idx & 127;
        float w = W[idx] + W[j * 128 + i];
        short h, l;
        split2(w, h, l);
        sH[i * 136 + j] = (unsigned short)h;
        sL[i * 136 + j] = (unsigned short)l;
    }
    __syncthreads();

    const int wid  = threadIdx.x >> 6;
    const int lane = threadIdx.x & 63;
    const int ar   = lane & 15;    // A row within 16 / B col within 16
    const int kg   = lane >> 4;    // k-subgroup: k = kg*8 + j
    const int row0 = blockIdx.x * 128 + wid * 16;
    const int gr   = row0 + ar;
    const bool rv  = gr < N;
    const float* fp = Fm + (size_t)gr * FDIM;

    f32x4 acc[8];
#pragma unroll
    for (int t = 0; t < 8; ++t) acc[t] = (f32x4){0.f, 0.f, 0.f, 0.f};

#pragma unroll
    for (int ks = 0; ks < 4; ++ks) {
        const int k0 = ks * 32 + kg * 8;
        float4 fa = make_float4(0.f, 0.f, 0.f, 0.f);
        float4 fb = make_float4(0.f, 0.f, 0.f, 0.f);
        if (rv) {
            fa = *(const float4*)(fp + k0);
            fb = *(const float4*)(fp + k0 + 4);
        }
        short8v ah, al;
        {
            short h, l;
            split2(fa.x, h, l); ah[0] = h; al[0] = l;
            split2(fa.y, h, l); ah[1] = h; al[1] = l;
            split2(fa.z, h, l); ah[2] = h; al[2] = l;
            split2(fa.w, h, l); ah[3] = h; al[3] = l;
            split2(fb.x, h, l); ah[4] = h; al[4] = l;
            split2(fb.y, h, l); ah[5] = h; al[5] = l;
            split2(fb.z, h, l); ah[6] = h; al[6] = l;
            split2(fb.w, h, l); ah[7] = h; al[7] = l;
        }
#pragma unroll
        for (int ct = 0; ct < 8; ++ct) {
            const short8v bh = *(const short8v*)(sH + (ct * 16 + ar) * 136 + k0);
            const short8v bl = *(const short8v*)(sL + (ct * 16 + ar) * 136 + k0);
            acc[ct] = __builtin_amdgcn_mfma_f32_16x16x32_bf16(ah, bh, acc[ct], 0, 0, 0);
            acc[ct] = __builtin_amdgcn_mfma_f32_16x16x32_bf16(ah, bl, acc[ct], 0, 0, 0);
            acc[ct] = __builtin_amdgcn_mfma_f32_16x16x32_bf16(al, bh, acc[ct], 0, 0, 0);
        }
    }

#pragma unroll
    for (int r = 0; r < 4; ++r) {
        const int orow = row0 + kg * 4 + r;
        if (orow < N) {
#pragma unroll
            for (int ct = 0; ct < 8; ++ct)
                Gbf[(size_t)orow * FDIM + ct * 16 + ar] = f2bf(acc[ct][r]);
        }
    }
}

// ---- k2: LDS histogram per partition block -> M[k][b]; block 0 also zeroes out[] ----
__global__ __launch_bounds__(256) void k_hist(const int* __restrict__ idx, int E,
                                              int nb, unsigned* __restrict__ M,
                                              float* __restrict__ out, int Mout) {
    if (blockIdx.x == 0) {
        for (int i = threadIdx.x; i < Mout; i += 256) out[i] = 0.f;
    }
    extern __shared__ unsigned cnt[];
    for (int i = threadIdx.x; i < nb; i += 256) cnt[i] = 0;
    __syncthreads();
    int chunk = (E + NBLK - 1) / NBLK;
    int s = blockIdx.x * chunk;
    int e_end = min(E, s + chunk);
    for (int e = s + threadIdx.x; e < e_end; e += 256) {
        int i1 = idx[E + e];
        atomicAdd(&cnt[i1 >> 5], 1u);
    }
    __syncthreads();
    for (int i = threadIdx.x; i < nb; i += 256)
        M[(size_t)blockIdx.x * nb + i] = cnt[i];
}

// ---- k3a: wave-per-bucket exclusive scan over k of M[k][b]; emits tot[b] ----
__global__ __launch_bounds__(256) void k_mscan2(unsigned* __restrict__ M, int nb,
                                                unsigned* __restrict__ tot) {
    int b = blockIdx.x * 4 + (threadIdx.x >> 6);
    int lane = threadIdx.x & 63;
    if (b >= nb) return;
    unsigned m0 = M[(size_t)(4 * lane + 0) * nb + b];
    unsigned m1 = M[(size_t)(4 * lane + 1) * nb + b];
    unsigned m2 = M[(size_t)(4 * lane + 2) * nb + b];
    unsigned m3 = M[(size_t)(4 * lane + 3) * nb + b];
    unsigned s = m0 + m1 + m2 + m3;
    unsigned incl = s;
#pragma unroll
    for (int d = 1; d < 64; d <<= 1) {
        unsigned u = __shfl_up(incl, d, 64);
        if (lane >= d) incl += u;
    }
    unsigned run = incl - s;   // exclusive prefix
    M[(size_t)(4 * lane + 0) * nb + b] = run; run += m0;
    M[(size_t)(4 * lane + 1) * nb + b] = run; run += m1;
    M[(size_t)(4 * lane + 2) * nb + b] = run; run += m2;
    M[(size_t)(4 * lane + 3) * nb + b] = run;
    if (lane == 63) tot[b] = incl;
}

// ---- k3b: single-block exclusive scan of tot -> bucketStart ----
__global__ __launch_bounds__(256) void k_bscan(const unsigned* __restrict__ tot, int nb,
                                               unsigned* __restrict__ bucketStart) {
    __shared__ unsigned wS[4];
    int t = threadIdx.x;
    unsigned v0, v1, v2, v3, v4, v5, v6, v7;
    int b0 = t * 8;
    v0 = (b0 + 0 < nb) ? tot[b0 + 0] : 0u;
    v1 = (b0 + 1 < nb) ? tot[b0 + 1] : 0u;
    v2 = (b0 + 2 < nb) ? tot[b0 + 2] : 0u;
    v3 = (b0 + 3 < nb) ? tot[b0 + 3] : 0u;
    v4 = (b0 + 4 < nb) ? tot[b0 + 4] : 0u;
    v5 = (b0 + 5 < nb) ? tot[b0 + 5] : 0u;
    v6 = (b0 + 6 < nb) ? tot[b0 + 6] : 0u;
    v7 = (b0 + 7 < nb) ? tot[b0 + 7] : 0u;
    unsigned l0 = 0, l1 = v0, l2 = l1 + v1, l3 = l2 + v2, l4 = l3 + v3,
             l5 = l4 + v4, l6 = l5 + v5, l7 = l6 + v6;
    unsigned s = l7 + v7;
    int lane = t & 63, wid = t >> 6;
    unsigned incl = s;
    for (int d = 1; d < 64; d <<= 1) {
        unsigned u = __shfl_up(incl, d, 64);
        if (lane >= d) incl += u;
    }
    if (lane == 63) wS[wid] = incl;
    __syncthreads();
    unsigned wOff = 0;
    for (int i = 0; i < wid; ++i) wOff += wS[i];
    unsigned base = wOff + incl - s;
    if (b0 + 0 < nb) bucketStart[b0 + 0] = base + l0;
    if (b0 + 1 < nb) bucketStart[b0 + 1] = base + l1;
    if (b0 + 2 < nb) bucketStart[b0 + 2] = base + l2;
    if (b0 + 3 < nb) bucketStart[b0 + 3] = base + l3;
    if (b0 + 4 < nb) bucketStart[b0 + 4] = base + l4;
    if (b0 + 5 < nb) bucketStart[b0 + 5] = base + l5;
    if (b0 + 6 < nb) bucketStart[b0 + 6] = base + l6;
    if (b0 + 7 < nb) bucketStart[b0 + 7] = base + l7;
    if (t == 255) bucketStart[nb] = base + s;
}

// ---- k4: scatter via LDS cursors (cursor = within-bucket prefix + bucketStart) ----
__global__ __launch_bounds__(256) void k_scatter(const int* __restrict__ idx,
                                                 const int* __restrict__ mol, int E,
                                                 int nb, const unsigned* __restrict__ M,
                                                 const unsigned* __restrict__ bucketStart,
                                                 unsigned* __restrict__ sortedE) {
    extern __shared__ unsigned cur[];
    for (int i = threadIdx.x; i < nb; i += 256)
        cur[i] = M[(size_t)blockIdx.x * nb + i] + bucketStart[i];
    __syncthreads();
    int chunk = (E + NBLK - 1) / NBLK;
    int s = blockIdx.x * chunk;
    int e_end = min(E, s + chunk);
    for (int e = s + threadIdx.x; e < e_end; e += 256) {
        int i0 = idx[e];
        int i1 = idx[E + e];
        int m  = mol[e];
        int b  = i1 >> 5;
        int loc = i1 & 31;
        unsigned pos = atomicAdd(&cur[b], 1u);
        sortedE[pos] = (unsigned)i0 | ((unsigned)m << 16) | ((unsigned)loc << 26);
    }
}

// ---- k5: edge kernel, MFMA version.
// Per 16-edge group: lane l gathers A = G-row of edge (l&15) (16B at k-slot lane>>4),
// B = LDS F-window row loc(l&15) (XOR-swizzled), 4x mfma_16x16x32 over K=128 produce
// all pairwise dots; diagonal C[e][e] sits in lane e+16*(e>>2), reg e&3 (layout
// HW-verified by gemm_mfma). smol flushed with skip-zero global atomics into out
// (k_red1/k_red2 + part buffer eliminated). ----
__global__ __launch_bounds__(512, 8) void edge_kernel(
    const unsigned short* __restrict__ Gbf, const float* __restrict__ Fm,
    const unsigned* __restrict__ sortedE, const unsigned* __restrict__ bucketStart,
    float* __restrict__ out, int N, int Mout) {
    __shared__ __align__(16) unsigned short sFrow[BROWS * FDIM];   // 8 KB, XOR-swizzled
    __shared__ float smol[1024];                                   // 4 KB

    const int b = blockIdx.x;
    const int row0 = b * BROWS;
    const int nrow = min(BROWS, N - row0);

    // stage F window as bf16 in 16B granules, swizzle: byte ^= (row&7)<<4
    for (int k = threadIdx.x; k < nrow * 16; k += 512) {
        int r = k >> 4, g = k & 15;                   // g = 16B granule within row
        const float4* src = (const float4*)(Fm + (size_t)(row0 + r) * FDIM + g * 8);
        float4 v0 = src[0], v1 = src[1];
        unsigned u0 = (unsigned)f2bf(v0.x) | ((unsigned)f2bf(v0.y) << 16);
        unsigned u1 = (unsigned)f2bf(v0.z) | ((unsigned)f2bf(v0.w) << 16);
        unsigned u2 = (unsigned)f2bf(v1.x) | ((unsigned)f2bf(v1.y) << 16);
        unsigned u3 = (unsigned)f2bf(v1.z) | ((unsigned)f2bf(v1.w) << 16);
        char* dst = (char*)sFrow + r * 256 + ((g * 16) ^ ((r & 7) << 4));
        *(uint4*)dst = make_uint4(u0, u1, u2, u3);
    }
    for (int i = threadIdx.x; i < 1024; i += 512) smol[i] = 0.f;
    __syncthreads();

    const int s = (int)bucketStart[b];
    const int e_end = (int)bucketStart[b + 1];
    const int lane = threadIdx.x & 63;
    const int wid  = threadIdx.x >> 6;
    const int er = lane & 15;      // edge slot within the 16-edge group
    const int kg = lane >> 4;      // k-subgroup (8 elems each)
    const bool isdiag = ((er >> 2) == kg);

    int base = s + wid * 16;
    unsigned pk = 0u;
    if (base + er < e_end && base < e_end) pk = sortedE[base + er];

    while (base < e_end) {
        const int nbase = base + 128;                 // 8 waves x 16 edges
        unsigned npk = 0u;
        if (nbase < e_end && nbase + er < e_end) npk = sortedE[nbase + er];

        const int i0  = pk & 0xffff;
        const int loc = pk >> 26;
        const unsigned short* gp = Gbf + (size_t)i0 * FDIM + kg * 8;
        const char* lp = (const char*)sFrow + loc * 256;
        const int swz = (loc & 7) << 4;

        f32x4 acc = (f32x4){0.f, 0.f, 0.f, 0.f};
#pragma unroll
        for (int ks = 0; ks < 4; ++ks) {
            short8v a  = *(const short8v*)(gp + ks * 32);
            short8v bf = *(const short8v*)(lp + ((ks * 64 + kg * 16) ^ swz));
            acc = __builtin_amdgcn_mfma_f32_16x16x32_bf16(a, bf, acc, 0, 0, 0);
        }
        if (isdiag && (base + er < e_end)) {
            atomicAdd(&smol[(pk >> 16) & 0x3ff], acc[er & 3]);
        }
        pk = npk;
        base = nbase;
    }
    __syncthreads();

    for (int i = threadIdx.x; i < Mout; i += 512) {
        float v = smol[i];
        if (v != 0.f) atomicAdd(&out[i], v);
    }
}

extern "C" void kernel_launch(void* const* d_in, const int* in_sizes, int n_in,
                              void* d_out, int out_size, void* d_ws, size_t ws_size,
                              hipStream_t stream) {
    const float* Fm = (const float*)d_in[0];
    const float* W  = (const float*)d_in[1];
    const int* idx  = (const int*)d_in[2];
    const int* mol  = (const int*)d_in[3];
    float* out = (float*)d_out;

    const int N = in_sizes[0] / FDIM;   // 50000
    const int E = in_sizes[3];          // 1600000

    const int nb = (N + BROWS - 1) / BROWS;   // 1563 buckets

    // workspace layout (~21 MB)
    char* ws = (char*)d_ws;
    size_t o = 0;
    unsigned short* Gbf = (unsigned short*)(ws + o); o += ((size_t)N * FDIM * 2 + 255) & ~(size_t)255;
    unsigned* sortedE = (unsigned*)(ws + o);         o += ((size_t)E * 4 + 255) & ~(size_t)255;
    unsigned* M = (unsigned*)(ws + o);               o += ((size_t)NBLK * nb * 4 + 255) & ~(size_t)255;
    unsigned* tot = (unsigned*)(ws + o);             o += ((size_t)nb * 4 + 255) & ~(size_t)255;
    unsigned* bucketStart = (unsigned*)(ws + o);     o += ((size_t)(nb + 1) * 4 + 255) & ~(size_t)255;

    gemm_mfma<<<(N + 127) / 128, 512, 0, stream>>>(Fm, W, Gbf, N);

    size_t smem = (size_t)nb * 4;
    k_hist<<<NBLK, 256, smem, stream>>>(idx, E, nb, M, out, out_size);
    k_mscan2<<<(nb + 3) / 4, 256, 0, stream>>>(M, nb, tot);
    k_bscan<<<1, 256, 0, stream>>>(tot, nb, bucketStart);
    k_scatter<<<NBLK, 256, smem, stream>>>(idx, mol, E, nb, M, bucketStart, sortedE);

    edge_kernel<<<nb, 512, 0, stream>>>(Gbf, Fm, sortedE, bucketStart, out, N, out_size);
}